// Round 2
// baseline (188.123 us; speedup 1.0000x reference)
//
#include <hip/hip_runtime.h>
#include <cstdint>
#include <cstddef>

#define NIMG 256
#define PADW 18
#define XB_IMG (PADW * PADW * 256)   // 82944 elements per image
#define W2_ROW 2304                  // 9*256

typedef __bf16 bf16x8 __attribute__((ext_vector_type(8)));
typedef float floatx4 __attribute__((ext_vector_type(4)));
typedef float floatvec4 __attribute__((ext_vector_type(4)));

__device__ __forceinline__ unsigned short f2bf(float f) {
    unsigned u = __float_as_uint(f);
    u = (u + 0x7FFFu + ((u >> 16) & 1u)) >> 16;   // RNE
    return (unsigned short)u;
}

__device__ __forceinline__ void gload_lds16(const void* g, void* l) {
    __builtin_amdgcn_global_load_lds(
        (const __attribute__((address_space(1))) void*)g,
        (__attribute__((address_space(3))) void*)l, 16, 0, 0);
}

// counted waits (T4): never drain vmcnt to 0 in the main loop.
#define VMCNT_LGKM0(n) asm volatile("s_waitcnt vmcnt(" #n ") lgkmcnt(0)" ::: "memory")

// ---------------------------------------------------------------------------
// prep_kernel: merged convert (blocks 0..1023) + wprep (blocks 1024..1167).
// (unchanged from round 1 — verified)
// ---------------------------------------------------------------------------
__global__ __launch_bounds__(256) void prep_kernel(
        const float* __restrict__ x, unsigned short* __restrict__ xb,
        const float* __restrict__ wt, const float* __restrict__ alphas,
        unsigned short* __restrict__ w2) {
    __shared__ __align__(16) char lds_pool[64 * 268 * 2];
    const int bx = blockIdx.x;
    const int t  = threadIdx.x;

    if (bx < 1024) {
        unsigned short (*tile2)[268] = (unsigned short (*)[268])lds_pool;
        const int n  = bx & 255;
        const int cy = bx >> 8;
        const int c0 = cy * 64;
        const float* xi = x + (size_t)n * 65536;
        unsigned short* xo = xb + (size_t)n * XB_IMG;

        if (cy == 0) {
            #pragma unroll
            for (int it = 0; it < 17; ++it) {
                int idx = it * 256 + t;
                int hp = idx >> 6;
                int c4 = (idx & 63) * 4;
                int py, px;
                if (hp < 18)      { py = 0;       px = hp;      }
                else if (hp < 36) { py = 17;      px = hp - 18; }
                else if (hp < 52) { py = hp - 35; px = 0;       }
                else              { py = hp - 51; px = 17;      }
                *(uint2*)&xo[(py * 18 + px) * 256 + c4] = make_uint2(0u, 0u);
            }
        }
        {
            const int p4 = (t & 63) * 4;
            const int ci = t >> 6;
            #pragma unroll
            for (int i = 0; i < 16; ++i) {
                const int c = i * 4 + ci;
                floatvec4 v = *(const floatvec4*)&xi[(c0 + c) * 256 + p4];
                unsigned lo = (unsigned)f2bf(v.x) | ((unsigned)f2bf(v.y) << 16);
                unsigned hi = (unsigned)f2bf(v.z) | ((unsigned)f2bf(v.w) << 16);
                *(uint2*)&tile2[c][p4] = make_uint2(lo, hi);
            }
        }
        __syncthreads();
        #pragma unroll
        for (int it = 0; it < 32; ++it) {
            int idx = it * 256 + t;
            int p   = idx >> 5;
            int cp  = (idx & 31) * 2;
            unsigned lo = tile2[cp][p];
            unsigned hi = tile2[cp + 1][p];
            int py = (p >> 4) + 1, px = (p & 15) + 1;
            *(unsigned int*)&xo[(py * 18 + px) * 256 + c0 + cp] = lo | (hi << 16);
        }
    } else {
        float (*wlds)[257] = (float (*)[257])lds_pool;
        const int w   = bx - 1024;
        const int o16 = (w & 15) * 16;
        const int pos = w >> 4;

        #pragma unroll
        for (int j = 0; j < 16; ++j)
            wlds[j][t] = wt[((o16 + j) * 256 + t) * 9 + pos];

        float a[5];
        {
            float mx = alphas[0];
            #pragma unroll
            for (int i = 1; i < 5; ++i) mx = fmaxf(mx, alphas[i]);
            float s = 0.f;
            #pragma unroll
            for (int i = 0; i < 5; ++i) { a[i] = __expf(alphas[i] - mx); s += a[i]; }
            float inv = 1.f / s;
            #pragma unroll
            for (int i = 0; i < 5; ++i) a[i] *= inv;
        }
        __syncthreads();

        const int c = t;
        #pragma unroll
        for (int oo = 0; oo < 16; ++oo) {
            float acc = a[0] * wlds[oo][c];
            #pragma unroll
            for (int bi = 0; bi < 4; ++bi) {
                const int b  = 2 << bi;            // 2,4,8,16
                const int r  = oo & (b - 1);
                const int cc = c & (b - 1);
                const int i0 = (r - cc) & (b - 1);
                const int ob = oo - r;
                const int icb = c - cc;
                float s2 = 0.f;
                for (int j = 0; j < b; ++j)
                    s2 += wlds[ob + j][icb + ((j + i0) & (b - 1))];
                acc += a[1 + bi] * s2 * (1.f / (float)b);
            }
            w2[(size_t)(o16 + oo) * W2_ROW + pos * 256 + c] = f2bf(acc);
        }
    }
}

// standalone wprep kept only for the small-workspace fallback path
__global__ __launch_bounds__(256) void wprep_kernel(
        const float* __restrict__ wt, const float* __restrict__ alphas,
        unsigned short* __restrict__ w2) {
    __shared__ float wlds[16][257];
    const int o16 = blockIdx.x * 16;
    const int pos = blockIdx.y;
    const int t   = threadIdx.x;
    #pragma unroll
    for (int j = 0; j < 16; ++j)
        wlds[j][t] = wt[((o16 + j) * 256 + t) * 9 + pos];
    float a[5];
    {
        float mx = alphas[0];
        #pragma unroll
        for (int i = 1; i < 5; ++i) mx = fmaxf(mx, alphas[i]);
        float s = 0.f;
        #pragma unroll
        for (int i = 0; i < 5; ++i) { a[i] = __expf(alphas[i] - mx); s += a[i]; }
        float inv = 1.f / s;
        #pragma unroll
        for (int i = 0; i < 5; ++i) a[i] *= inv;
    }
    __syncthreads();
    const int c = t;
    #pragma unroll
    for (int oo = 0; oo < 16; ++oo) {
        float acc = a[0] * wlds[oo][c];
        #pragma unroll
        for (int bi = 0; bi < 4; ++bi) {
            const int b  = 2 << bi;
            const int r  = oo & (b - 1);
            const int cc = c & (b - 1);
            const int i0 = (r - cc) & (b - 1);
            const int ob = oo - r;
            const int icb = c - cc;
            float s2 = 0.f;
            for (int j = 0; j < b; ++j)
                s2 += wlds[ob + j][icb + ((j + i0) & (b - 1))];
            acc += a[1 + bi] * s2 * (1.f / (float)b);
        }
        w2[(size_t)(o16 + oo) * W2_ROW + pos * 256 + c] = f2bf(acc);
    }
}

// ---------------------------------------------------------------------------
// gemm_kernel v7: same 256x256 geometry / swizzle / staging as v6 (verified),
// new SCHEDULE = m201 8-phase port:
//   per 32-K half-step: 2 quadrant phases of 16 MFMA each, 3 barriers,
//   counted vmcnt(8) only at the publish barrier, lgkmcnt(0)+sched_barrier(0)
//   pinning before each MFMA cluster, setprio(1) around MFMA (T5).
// K-order changed to pos-INNER (hs = c32*9 + pos) so re-reads of the same xb
// cachelines are 1 half-step apart -> L2-resident (fixes the 93 MB FETCH).
// ---------------------------------------------------------------------------
__global__ __launch_bounds__(512, 2) void gemm_kernel(
        const unsigned short* __restrict__ xb,
        const unsigned short* __restrict__ w2,
        float* __restrict__ out) {
    extern __shared__ __align__(16) char smem[];
    unsigned short* const xs = (unsigned short*)smem;            // 4 x 8192 elems (B: pixels)
    unsigned short* const ws = (unsigned short*)(smem + 65536);  // 4 x 8192 elems (A: kout)

    const int t     = threadIdx.x;
    const int lane  = t & 63;
    const int wid   = t >> 6;
    const int n_img = blockIdx.x;

    // ---- staging setup: waves 0-3 stage XS (pixels), waves 4-7 stage WS ----
    const int q     = lane >> 2;
    const int kswz  = ((lane & 3) - ((lane >> 3) & 3)) & 3;  // source k-slot for phys slot lane&3
    const int choff = kswz * 8;
    const unsigned short* sbase;
    int sg[4];
    int ldst;
    if (wid < 4) {
        sbase = xb;
        #pragma unroll
        for (int i = 0; i < 4; ++i) {
            const int r = wid * 64 + i * 16 + q;       // pixel 0..255
            const int y = r >> 4, xx = r & 15;
            sg[i] = n_img * XB_IMG + ((y + 1) * 18 + (xx + 1)) * 256 + choff;
        }
        ldst = wid * 4096;                             // byte offset in buffer
    } else {
        sbase = w2;
        const int wv = wid - 4;
        #pragma unroll
        for (int i = 0; i < 4; ++i) {
            const int r = wv * 64 + i * 16 + q;        // kout 0..255
            sg[i] = r * W2_ROW + choff;
        }
        ldst = (wid - 4) * 4096;
    }
    const bool is_x = (wid < 4);

    // issue 2 of the 4 staging gloads for half-step hsp into buffer (px,pw)
    auto issue2 = [&](int hsp, char* px, char* pw, int i0) {
        const int c32 = hsp / 9, pos = hsp - c32 * 9;   // pos INNER in K order
        int go; char* dst;
        if (is_x) {
            const int dy = pos / 3, dxp = pos - dy * 3;
            go  = (dy - 1) * 4608 + (dxp - 1) * 256 + c32 * 32;
            dst = px + ldst;
        } else {
            go  = pos * 256 + c32 * 32;
            dst = pw + ldst;
        }
        gload_lds16(sbase + sg[i0]     + go, dst + i0 * 1024);
        gload_lds16(sbase + sg[i0 + 1] + go, dst + (i0 + 1) * 1024);
    };

    // ---- compute setup: wave (wr,wc) owns kout [wr*128,+128) x pix [wc*64,+64)
    const int wr   = wid >> 2, wc = wid & 3;
    const int slot = ((lane >> 1) + (lane >> 4)) & 3;  // proven 0-conflict swizzle
    const int aoff = (wr * 128 + (lane & 15)) * 32 + slot * 8;
    const int boff = (wc * 64  + (lane & 15)) * 32 + slot * 8;

    const floatx4 z4 = {0.f, 0.f, 0.f, 0.f};
    floatx4 acc[8][4];
    #pragma unroll
    for (int i = 0; i < 8; ++i)
        #pragma unroll
        for (int j = 0; j < 4; ++j) acc[i][j] = z4;

    unsigned short* const xs0 = xs,         * const ws0 = ws;
    unsigned short* const xs1 = xs + 8192,  * const ws1 = ws + 8192;
    unsigned short* const xs2 = xs + 16384, * const ws2 = ws + 16384;
    unsigned short* const xs3 = xs + 24576, * const ws3 = ws + 24576;

// one 32-K half-step: publish barrier + two quadrant phases (m201 schedule)
#define HALF(CX, CW, PX, PW, HSP, DOISS, N) do {                              \
    VMCNT_LGKM0(N);                                                           \
    __builtin_amdgcn_s_barrier();                                             \
    bf16x8 afq[4], bq[4];                                                     \
    _Pragma("unroll")                                                         \
    for (int mt = 0; mt < 4; ++mt)                                            \
        afq[mt] = *(const bf16x8*)&(CW)[aoff + mt * 512];                     \
    _Pragma("unroll")                                                         \
    for (int nt = 0; nt < 4; ++nt)                                            \
        bq[nt] = *(const bf16x8*)&(CX)[boff + nt * 512];                      \
    if (DOISS) issue2((HSP), (char*)(PX), (char*)(PW), 0);                    \
    __builtin_amdgcn_s_barrier();                                             \
    asm volatile("s_waitcnt lgkmcnt(0)" ::: "memory");                        \
    __builtin_amdgcn_sched_barrier(0);                                        \
    __builtin_amdgcn_s_setprio(1);                                            \
    _Pragma("unroll")                                                         \
    for (int mt = 0; mt < 4; ++mt)                                            \
        _Pragma("unroll")                                                     \
        for (int nt = 0; nt < 4; ++nt)                                        \
            acc[mt][nt] = __builtin_amdgcn_mfma_f32_16x16x32_bf16(            \
                afq[mt], bq[nt], acc[mt][nt], 0, 0, 0);                       \
    __builtin_amdgcn_s_setprio(0);                                            \
    bf16x8 agq[4];                                                            \
    _Pragma("unroll")                                                         \
    for (int mt = 0; mt < 4; ++mt)                                            \
        agq[mt] = *(const bf16x8*)&(CW)[aoff + (mt + 4) * 512];               \
    if (DOISS) issue2((HSP), (char*)(PX), (char*)(PW), 2);                    \
    __builtin_amdgcn_s_barrier();                                             \
    asm volatile("s_waitcnt lgkmcnt(0)" ::: "memory");                        \
    __builtin_amdgcn_sched_barrier(0);                                        \
    __builtin_amdgcn_s_setprio(1);                                            \
    _Pragma("unroll")                                                         \
    for (int mt = 0; mt < 4; ++mt)                                            \
        _Pragma("unroll")                                                     \
        for (int nt = 0; nt < 4; ++nt)                                        \
            acc[mt + 4][nt] = __builtin_amdgcn_mfma_f32_16x16x32_bf16(        \
                agq[mt], bq[nt], acc[mt + 4][nt], 0, 0, 0);                   \
    __builtin_amdgcn_s_setprio(0);                                            \
} while (0)

    // prologue: 3 half-steps in flight (4 loads each per wave = 12 vmcnt events)
    issue2(0, (char*)xs0, (char*)ws0, 0); issue2(0, (char*)xs0, (char*)ws0, 2);
    issue2(1, (char*)xs1, (char*)ws1, 0); issue2(1, (char*)xs1, (char*)ws1, 2);
    issue2(2, (char*)xs2, (char*)ws2, 0); issue2(2, (char*)xs2, (char*)ws2, 2);

    int hs = 0;
    #pragma unroll 1
    for (int it = 0; it < 17; ++it) {          // consumes hs 0..67, issues 3..70
        HALF(xs0, ws0, xs3, ws3, hs + 3, true, 8);
        HALF(xs1, ws1, xs0, ws0, hs + 4, true, 8);
        HALF(xs2, ws2, xs1, ws1, hs + 5, true, 8);
        HALF(xs3, ws3, xs2, ws2, hs + 6, true, 8);
        hs += 4;
    }
    // tail: consume 68..71; issue 71; drain 8 -> 8 -> 4 -> 0
    HALF(xs0, ws0, xs3, ws3, 71, true,  8);
    HALF(xs1, ws1, xs0, ws0, 0,  false, 8);
    HALF(xs2, ws2, xs0, ws0, 0,  false, 4);
    HALF(xs3, ws3, xs0, ws0, 0,  false, 0);
#undef HALF

    // ---- epilogue: C/D 16x16 layout col=lane&15 (pixel), row=(lane>>4)*4+r
    float* ob = out + (size_t)n_img * 65536;
    const int kb = wr * 128 + (lane >> 4) * 4;
    const int pb = wc * 64 + (lane & 15);
    #pragma unroll
    for (int mt = 0; mt < 8; ++mt)
        #pragma unroll
        for (int nt = 0; nt < 4; ++nt) {
            const int kout = kb + mt * 16;
            const int p    = pb + nt * 16;
            #pragma unroll
            for (int r = 0; r < 4; ++r)
                ob[(size_t)(kout + r) * 256 + p] = acc[mt][nt][r];
        }
}

// ---------------------------------------------------------------------------
// Fallback (only if workspace too small for xb): naive conv using w2.
// ---------------------------------------------------------------------------
__global__ __launch_bounds__(256) void naive_conv(
        const float* __restrict__ x, const unsigned short* __restrict__ w2,
        float* __restrict__ out) {
    __shared__ float wr[2304];
    const int n = blockIdx.x >> 8, k = blockIdx.x & 255;
    const int t = threadIdx.x;
    for (int i = t; i < 2304; i += 256)
        wr[i] = __uint_as_float(((unsigned)w2[k * W2_ROW + i]) << 16);
    __syncthreads();
    const int y = t >> 4, xx = t & 15;
    const float* xi = x + (size_t)n * 65536;
    float acc = 0.f;
    for (int pos = 0; pos < 9; ++pos) {
        int dy = pos / 3 - 1, dx = pos % 3 - 1;
        int yy = y + dy, x2 = xx + dx;
        if (yy < 0 || yy > 15 || x2 < 0 || x2 > 15) continue;
        const float* xp = xi + yy * 16 + x2;
        const float* wp = wr + pos * 256;
        for (int c = 0; c < 256; ++c) acc += xp[c * 256] * wp[c];
    }
    out[(size_t)n * 65536 + k * 256 + t] = acc;
}

extern "C" void kernel_launch(void* const* d_in, const int* in_sizes, int n_in,
                              void* d_out, int out_size, void* d_ws, size_t ws_size,
                              hipStream_t stream) {
    const float* x      = (const float*)d_in[0];
    const float* wt     = (const float*)d_in[1];
    const float* alphas = (const float*)d_in[2];
    float* out = (float*)d_out;

    const size_t xb_elems = (size_t)NIMG * XB_IMG;          // 21,233,664
    const size_t w2_elems = (size_t)256 * W2_ROW;           //    589,824
    const size_t need = (xb_elems + w2_elems) * sizeof(unsigned short);

    if (ws_size >= need) {
        unsigned short* xbp = (unsigned short*)d_ws;
        unsigned short* w2p = xbp + xb_elems;
        static bool attr_done = false;
        if (!attr_done) {
            (void)hipFuncSetAttribute(reinterpret_cast<const void*>(&gemm_kernel),
                                      hipFuncAttributeMaxDynamicSharedMemorySize,
                                      131072);
            attr_done = true;
        }
        prep_kernel<<<dim3(1168), 256, 0, stream>>>(x, xbp, wt, alphas, w2p);
        gemm_kernel<<<dim3(256), 512, 131072, stream>>>(xbp, w2p, out);
    } else if (ws_size >= w2_elems * sizeof(unsigned short)) {
        unsigned short* w2p = (unsigned short*)d_ws;
        wprep_kernel<<<dim3(16, 9), 256, 0, stream>>>(wt, alphas, w2p);
        naive_conv<<<dim3(256 * 256), 256, 0, stream>>>(x, w2p, out);
    }
}

// Round 3
// 187.475 us; speedup vs baseline: 1.0035x; 1.0035x over previous
//
#include <hip/hip_runtime.h>
#include <cstdint>
#include <cstddef>

#define NIMG 256
#define PADW 18
#define XB_IMG (PADW * PADW * 256)   // 82944 elements per image
#define W2_ROW 2304                  // 9*256

typedef __bf16 bf16x8 __attribute__((ext_vector_type(8)));
typedef float floatx4 __attribute__((ext_vector_type(4)));
typedef float floatvec4 __attribute__((ext_vector_type(4)));

__device__ __forceinline__ unsigned short f2bf(float f) {
    unsigned u = __float_as_uint(f);
    u = (u + 0x7FFFu + ((u >> 16) & 1u)) >> 16;   // RNE
    return (unsigned short)u;
}

__device__ __forceinline__ void gload_lds16(const void* g, void* l) {
    __builtin_amdgcn_global_load_lds(
        (const __attribute__((address_space(1))) void*)g,
        (__attribute__((address_space(3))) void*)l, 16, 0, 0);
}

// ---------------------------------------------------------------------------
// prep_kernel: merged convert (blocks 0..1023) + wprep (blocks 1024..1167).
// (unchanged — verified)
// ---------------------------------------------------------------------------
__global__ __launch_bounds__(256) void prep_kernel(
        const float* __restrict__ x, unsigned short* __restrict__ xb,
        const float* __restrict__ wt, const float* __restrict__ alphas,
        unsigned short* __restrict__ w2) {
    __shared__ __align__(16) char lds_pool[64 * 268 * 2];
    const int bx = blockIdx.x;
    const int t  = threadIdx.x;

    if (bx < 1024) {
        unsigned short (*tile2)[268] = (unsigned short (*)[268])lds_pool;
        const int n  = bx & 255;
        const int cy = bx >> 8;
        const int c0 = cy * 64;
        const float* xi = x + (size_t)n * 65536;
        unsigned short* xo = xb + (size_t)n * XB_IMG;

        if (cy == 0) {
            #pragma unroll
            for (int it = 0; it < 17; ++it) {
                int idx = it * 256 + t;
                int hp = idx >> 6;
                int c4 = (idx & 63) * 4;
                int py, px;
                if (hp < 18)      { py = 0;       px = hp;      }
                else if (hp < 36) { py = 17;      px = hp - 18; }
                else if (hp < 52) { py = hp - 35; px = 0;       }
                else              { py = hp - 51; px = 17;      }
                *(uint2*)&xo[(py * 18 + px) * 256 + c4] = make_uint2(0u, 0u);
            }
        }
        {
            const int p4 = (t & 63) * 4;
            const int ci = t >> 6;
            #pragma unroll
            for (int i = 0; i < 16; ++i) {
                const int c = i * 4 + ci;
                floatvec4 v = *(const floatvec4*)&xi[(c0 + c) * 256 + p4];
                unsigned lo = (unsigned)f2bf(v.x) | ((unsigned)f2bf(v.y) << 16);
                unsigned hi = (unsigned)f2bf(v.z) | ((unsigned)f2bf(v.w) << 16);
                *(uint2*)&tile2[c][p4] = make_uint2(lo, hi);
            }
        }
        __syncthreads();
        #pragma unroll
        for (int it = 0; it < 32; ++it) {
            int idx = it * 256 + t;
            int p   = idx >> 5;
            int cp  = (idx & 31) * 2;
            unsigned lo = tile2[cp][p];
            unsigned hi = tile2[cp + 1][p];
            int py = (p >> 4) + 1, px = (p & 15) + 1;
            *(unsigned int*)&xo[(py * 18 + px) * 256 + c0 + cp] = lo | (hi << 16);
        }
    } else {
        float (*wlds)[257] = (float (*)[257])lds_pool;
        const int w   = bx - 1024;
        const int o16 = (w & 15) * 16;
        const int pos = w >> 4;

        #pragma unroll
        for (int j = 0; j < 16; ++j)
            wlds[j][t] = wt[((o16 + j) * 256 + t) * 9 + pos];

        float a[5];
        {
            float mx = alphas[0];
            #pragma unroll
            for (int i = 1; i < 5; ++i) mx = fmaxf(mx, alphas[i]);
            float s = 0.f;
            #pragma unroll
            for (int i = 0; i < 5; ++i) { a[i] = __expf(alphas[i] - mx); s += a[i]; }
            float inv = 1.f / s;
            #pragma unroll
            for (int i = 0; i < 5; ++i) a[i] *= inv;
        }
        __syncthreads();

        const int c = t;
        #pragma unroll
        for (int oo = 0; oo < 16; ++oo) {
            float acc = a[0] * wlds[oo][c];
            #pragma unroll
            for (int bi = 0; bi < 4; ++bi) {
                const int b  = 2 << bi;            // 2,4,8,16
                const int r  = oo & (b - 1);
                const int cc = c & (b - 1);
                const int i0 = (r - cc) & (b - 1);
                const int ob = oo - r;
                const int icb = c - cc;
                float s2 = 0.f;
                for (int j = 0; j < b; ++j)
                    s2 += wlds[ob + j][icb + ((j + i0) & (b - 1))];
                acc += a[1 + bi] * s2 * (1.f / (float)b);
            }
            w2[(size_t)(o16 + oo) * W2_ROW + pos * 256 + c] = f2bf(acc);
        }
    }
}

// standalone wprep kept only for the small-workspace fallback path
__global__ __launch_bounds__(256) void wprep_kernel(
        const float* __restrict__ wt, const float* __restrict__ alphas,
        unsigned short* __restrict__ w2) {
    __shared__ float wlds[16][257];
    const int o16 = blockIdx.x * 16;
    const int pos = blockIdx.y;
    const int t   = threadIdx.x;
    #pragma unroll
    for (int j = 0; j < 16; ++j)
        wlds[j][t] = wt[((o16 + j) * 256 + t) * 9 + pos];
    float a[5];
    {
        float mx = alphas[0];
        #pragma unroll
        for (int i = 1; i < 5; ++i) mx = fmaxf(mx, alphas[i]);
        float s = 0.f;
        #pragma unroll
        for (int i = 0; i < 5; ++i) { a[i] = __expf(alphas[i] - mx); s += a[i]; }
        float inv = 1.f / s;
        #pragma unroll
        for (int i = 0; i < 5; ++i) a[i] *= inv;
    }
    __syncthreads();
    const int c = t;
    #pragma unroll
    for (int oo = 0; oo < 16; ++oo) {
        float acc = a[0] * wlds[oo][c];
        #pragma unroll
        for (int bi = 0; bi < 4; ++bi) {
            const int b  = 2 << bi;
            const int r  = oo & (b - 1);
            const int cc = c & (b - 1);
            const int i0 = (r - cc) & (b - 1);
            const int ob = oo - r;
            const int icb = c - cc;
            float s2 = 0.f;
            for (int j = 0; j < b; ++j)
                s2 += wlds[ob + j][icb + ((j + i0) & (b - 1))];
            acc += a[1 + bi] * s2 * (1.f / (float)b);
        }
        w2[(size_t)(o16 + oo) * W2_ROW + pos * 256 + c] = f2bf(acc);
    }
}

// ---------------------------------------------------------------------------
// gemm_kernel v8: same geometry/swizzle/staging/ring-4 as v7 (verified),
// new DERIVED-WAITS schedule per 32-K half-step:
//   vmcnt(N) -> barrier -> issue reads B(4),A0(4) -> stage 4 gloads ->
//   issue reads A1(4) -> lgkmcnt(4) -> 16 MFMA Q0 -> lgkmcnt(0) -> 16 MFMA Q1.
// A1's LDS drain hides under Q0's MFMAs; next step's read drain hides under
// Q1 + the vmcnt/barrier window. ONE barrier per half-step (72 total).
// Buffer-reuse safety: every wave retires all reads (lgkmcnt(0)) before Q1,
// hence before the next barrier, so staging into slot h-1 after barrier h
// cannot race any read.
// ---------------------------------------------------------------------------
__global__ __launch_bounds__(512, 2) void gemm_kernel(
        const unsigned short* __restrict__ xb,
        const unsigned short* __restrict__ w2,
        float* __restrict__ out) {
    extern __shared__ __align__(16) char smem[];
    unsigned short* const xs = (unsigned short*)smem;            // 4 x 8192 elems (B: pixels)
    unsigned short* const ws = (unsigned short*)(smem + 65536);  // 4 x 8192 elems (A: kout)

    const int t     = threadIdx.x;
    const int lane  = t & 63;
    const int wid   = t >> 6;
    const int n_img = blockIdx.x;

    // ---- staging setup: waves 0-3 stage XS (pixels), waves 4-7 stage WS ----
    const int q     = lane >> 2;
    const int kswz  = ((lane & 3) - ((lane >> 3) & 3)) & 3;  // source k-slot for phys slot lane&3
    const int choff = kswz * 8;
    const unsigned short* sbase;
    int sg[4];
    int ldst;
    if (wid < 4) {
        sbase = xb;
        #pragma unroll
        for (int i = 0; i < 4; ++i) {
            const int r = wid * 64 + i * 16 + q;       // pixel 0..255
            const int y = r >> 4, xx = r & 15;
            sg[i] = n_img * XB_IMG + ((y + 1) * 18 + (xx + 1)) * 256 + choff;
        }
        ldst = wid * 4096;                             // byte offset in buffer
    } else {
        sbase = w2;
        const int wv = wid - 4;
        #pragma unroll
        for (int i = 0; i < 4; ++i) {
            const int r = wv * 64 + i * 16 + q;        // kout 0..255
            sg[i] = r * W2_ROW + choff;
        }
        ldst = (wid - 4) * 4096;
    }
    const bool is_x = (wid < 4);

    // issue 2 of the 4 staging gloads for half-step hsp into buffer (px,pw)
    auto issue2 = [&](int hsp, char* px, char* pw, int i0) {
        const int c32 = hsp / 9, pos = hsp - c32 * 9;   // pos INNER in K order
        int go; char* dst;
        if (is_x) {
            const int dy = pos / 3, dxp = pos - dy * 3;
            go  = (dy - 1) * 4608 + (dxp - 1) * 256 + c32 * 32;
            dst = px + ldst;
        } else {
            go  = pos * 256 + c32 * 32;
            dst = pw + ldst;
        }
        gload_lds16(sbase + sg[i0]     + go, dst + i0 * 1024);
        gload_lds16(sbase + sg[i0 + 1] + go, dst + (i0 + 1) * 1024);
    };

    // ---- compute setup: wave (wr,wc) owns kout [wr*128,+128) x pix [wc*64,+64)
    const int wr   = wid >> 2, wc = wid & 3;
    const int slot = ((lane >> 1) + (lane >> 4)) & 3;  // proven 0-conflict swizzle
    const int aoff = (wr * 128 + (lane & 15)) * 32 + slot * 8;
    const int boff = (wc * 64  + (lane & 15)) * 32 + slot * 8;

    const floatx4 z4 = {0.f, 0.f, 0.f, 0.f};
    floatx4 acc[8][4];
    #pragma unroll
    for (int i = 0; i < 8; ++i)
        #pragma unroll
        for (int j = 0; j < 4; ++j) acc[i][j] = z4;

    unsigned short* const xs0 = xs,         * const ws0 = ws;
    unsigned short* const xs1 = xs + 8192,  * const ws1 = ws + 8192;
    unsigned short* const xs2 = xs + 16384, * const ws2 = ws + 16384;
    unsigned short* const xs3 = xs + 24576, * const ws3 = ws + 24576;

// one 32-K half-step with derived (counted) lgkm waits
#define STEP(CX, CW, PX, PW, HSP, DOISS, N) do {                              \
    asm volatile("s_waitcnt vmcnt(" #N ")" ::: "memory");                     \
    __builtin_amdgcn_s_barrier();                                             \
    bf16x8 bq[4], a0q[4], a1q[4];                                             \
    _Pragma("unroll")                                                         \
    for (int nt = 0; nt < 4; ++nt)                                            \
        bq[nt] = *(const bf16x8*)&(CX)[boff + nt * 512];                      \
    _Pragma("unroll")                                                         \
    for (int mt = 0; mt < 4; ++mt)                                            \
        a0q[mt] = *(const bf16x8*)&(CW)[aoff + mt * 512];                     \
    if (DOISS) { issue2((HSP), (char*)(PX), (char*)(PW), 0);                  \
                 issue2((HSP), (char*)(PX), (char*)(PW), 2); }                \
    _Pragma("unroll")                                                         \
    for (int mt = 0; mt < 4; ++mt)                                            \
        a1q[mt] = *(const bf16x8*)&(CW)[aoff + (mt + 4) * 512];               \
    asm volatile("s_waitcnt lgkmcnt(4)" ::: "memory");                        \
    __builtin_amdgcn_sched_barrier(0);                                        \
    __builtin_amdgcn_s_setprio(1);                                            \
    _Pragma("unroll")                                                         \
    for (int mt = 0; mt < 4; ++mt)                                            \
        _Pragma("unroll")                                                     \
        for (int nt = 0; nt < 4; ++nt)                                        \
            acc[mt][nt] = __builtin_amdgcn_mfma_f32_16x16x32_bf16(            \
                a0q[mt], bq[nt], acc[mt][nt], 0, 0, 0);                       \
    __builtin_amdgcn_s_setprio(0);                                            \
    asm volatile("s_waitcnt lgkmcnt(0)" ::: "memory");                        \
    __builtin_amdgcn_sched_barrier(0);                                        \
    __builtin_amdgcn_s_setprio(1);                                            \
    _Pragma("unroll")                                                         \
    for (int mt = 0; mt < 4; ++mt)                                            \
        _Pragma("unroll")                                                     \
        for (int nt = 0; nt < 4; ++nt)                                        \
            acc[mt + 4][nt] = __builtin_amdgcn_mfma_f32_16x16x32_bf16(        \
                a1q[mt], bq[nt], acc[mt + 4][nt], 0, 0, 0);                   \
    __builtin_amdgcn_s_setprio(0);                                            \
} while (0)

    // prologue: 3 half-steps in flight (4 loads each per wave = 12 vmcnt events)
    issue2(0, (char*)xs0, (char*)ws0, 0); issue2(0, (char*)xs0, (char*)ws0, 2);
    issue2(1, (char*)xs1, (char*)ws1, 0); issue2(1, (char*)xs1, (char*)ws1, 2);
    issue2(2, (char*)xs2, (char*)ws2, 0); issue2(2, (char*)xs2, (char*)ws2, 2);

    int hs = 0;
    #pragma unroll 1
    for (int it = 0; it < 17; ++it) {          // consumes hs 0..67, issues 3..70
        STEP(xs0, ws0, xs3, ws3, hs + 3, true, 8);
        STEP(xs1, ws1, xs0, ws0, hs + 4, true, 8);
        STEP(xs2, ws2, xs1, ws1, hs + 5, true, 8);
        STEP(xs3, ws3, xs2, ws2, hs + 6, true, 8);
        hs += 4;
    }
    // tail: consume 68..71; issue 71; drain 8 -> 8 -> 4 -> 0
    STEP(xs0, ws0, xs3, ws3, 71, true,  8);
    STEP(xs1, ws1, xs0, ws0, 0,  false, 8);
    STEP(xs2, ws2, xs0, ws0, 0,  false, 4);
    STEP(xs3, ws3, xs0, ws0, 0,  false, 0);
#undef STEP

    // ---- epilogue: C/D 16x16 layout col=lane&15 (pixel), row=(lane>>4)*4+r
    float* ob = out + (size_t)n_img * 65536;
    const int kb = wr * 128 + (lane >> 4) * 4;
    const int pb = wc * 64 + (lane & 15);
    #pragma unroll
    for (int mt = 0; mt < 8; ++mt)
        #pragma unroll
        for (int nt = 0; nt < 4; ++nt) {
            const int kout = kb + mt * 16;
            const int p    = pb + nt * 16;
            #pragma unroll
            for (int r = 0; r < 4; ++r)
                ob[(size_t)(kout + r) * 256 + p] = acc[mt][nt][r];
        }
}

// ---------------------------------------------------------------------------
// Fallback (only if workspace too small for xb): naive conv using w2.
// ---------------------------------------------------------------------------
__global__ __launch_bounds__(256) void naive_conv(
        const float* __restrict__ x, const unsigned short* __restrict__ w2,
        float* __restrict__ out) {
    __shared__ float wr[2304];
    const int n = blockIdx.x >> 8, k = blockIdx.x & 255;
    const int t = threadIdx.x;
    for (int i = t; i < 2304; i += 256)
        wr[i] = __uint_as_float(((unsigned)w2[k * W2_ROW + i]) << 16);
    __syncthreads();
    const int y = t >> 4, xx = t & 15;
    const float* xi = x + (size_t)n * 65536;
    float acc = 0.f;
    for (int pos = 0; pos < 9; ++pos) {
        int dy = pos / 3 - 1, dx = pos % 3 - 1;
        int yy = y + dy, x2 = xx + dx;
        if (yy < 0 || yy > 15 || x2 < 0 || x2 > 15) continue;
        const float* xp = xi + yy * 16 + x2;
        const float* wp = wr + pos * 256;
        for (int c = 0; c < 256; ++c) acc += xp[c * 256] * wp[c];
    }
    out[(size_t)n * 65536 + k * 256 + t] = acc;
}

extern "C" void kernel_launch(void* const* d_in, const int* in_sizes, int n_in,
                              void* d_out, int out_size, void* d_ws, size_t ws_size,
                              hipStream_t stream) {
    const float* x      = (const float*)d_in[0];
    const float* wt     = (const float*)d_in[1];
    const float* alphas = (const float*)d_in[2];
    float* out = (float*)d_out;

    const size_t xb_elems = (size_t)NIMG * XB_IMG;          // 21,233,664
    const size_t w2_elems = (size_t)256 * W2_ROW;           //    589,824
    const size_t need = (xb_elems + w2_elems) * sizeof(unsigned short);

    if (ws_size >= need) {
        unsigned short* xbp = (unsigned short*)d_ws;
        unsigned short* w2p = xbp + xb_elems;
        static bool attr_done = false;
        if (!attr_done) {
            (void)hipFuncSetAttribute(reinterpret_cast<const void*>(&gemm_kernel),
                                      hipFuncAttributeMaxDynamicSharedMemorySize,
                                      131072);
            attr_done = true;
        }
        prep_kernel<<<dim3(1168), 256, 0, stream>>>(x, xbp, wt, alphas, w2p);
        gemm_kernel<<<dim3(256), 512, 131072, stream>>>(xbp, w2p, out);
    } else if (ws_size >= w2_elems * sizeof(unsigned short)) {
        unsigned short* w2p = (unsigned short*)d_ws;
        wprep_kernel<<<dim3(16, 9), 256, 0, stream>>>(wt, alphas, w2p);
        naive_conv<<<dim3(256 * 256), 256, 0, stream>>>(x, w2p, out);
    }
}

// Round 5
// 184.624 us; speedup vs baseline: 1.0190x; 1.0154x over previous
//
#include <hip/hip_runtime.h>
#include <cstdint>
#include <cstddef>

#define NIMG 256
#define PADW 18
#define XB_IMG (PADW * PADW * 256)   // 82944 elements per image (= 8 slabs x 10368)
#define SLAB_ELEMS (324 * 32)        // 10368 elems per (image, c32) slab
#define W2_ROW 2304                  // 9*256

typedef __bf16 bf16x8 __attribute__((ext_vector_type(8)));
typedef float floatx4 __attribute__((ext_vector_type(4)));
typedef float floatvec4 __attribute__((ext_vector_type(4)));

__device__ __forceinline__ unsigned short f2bf(float f) {
    unsigned u = __float_as_uint(f);
    u = (u + 0x7FFFu + ((u >> 16) & 1u)) >> 16;   // RNE
    return (unsigned short)u;
}

__device__ __forceinline__ void gload_lds16(const void* g, void* l) {
    __builtin_amdgcn_global_load_lds(
        (const __attribute__((address_space(1))) void*)g,
        (__attribute__((address_space(3))) void*)l, 16, 0, 0);
}

// ---------------------------------------------------------------------------
// prep_kernel: merged convert (blocks 0..1023) + wprep (blocks 1024..1167).
// convert writes xb in c32-blocked SLAB layout with the bank swizzle baked in:
//   xb[n][c32][r][unit], r = py*18+px (padded 18x18),
//   unit u holds channel-octet ks with u = (ks + ((r>>1)&3)) & 3.
// Halo rows written as zeros (so gemm slabs need no zeroing).
// ---------------------------------------------------------------------------
__global__ __launch_bounds__(256) void prep_kernel(
        const float* __restrict__ x, unsigned short* __restrict__ xb,
        const float* __restrict__ wt, const float* __restrict__ alphas,
        unsigned short* __restrict__ w2) {
    __shared__ __align__(16) char lds_pool[64 * 268 * 2];
    const int bx = blockIdx.x;
    const int t  = threadIdx.x;

    if (bx < 1024) {
        unsigned short (*tile2)[268] = (unsigned short (*)[268])lds_pool;
        const int n  = bx & 255;
        const int cy = bx >> 8;                      // 0..3 (64-channel group)
        const int c0 = cy * 64;
        const float* xi = x + (size_t)n * 65536;
        unsigned short* xo = xb + (size_t)n * XB_IMG;

        if (cy == 0) {
            // halo rows of ALL 8 slabs -> zeros
            if (t < 68) {
                int hp = t;
                int py, px;
                if (hp < 18)      { py = 0;       px = hp;      }
                else if (hp < 36) { py = 17;      px = hp - 18; }
                else if (hp < 52) { py = hp - 35; px = 0;       }
                else              { py = hp - 51; px = 17;      }
                const int r = py * 18 + px;
                const uint4 z = make_uint4(0u, 0u, 0u, 0u);
                #pragma unroll
                for (int sl = 0; sl < 8; ++sl) {
                    unsigned short* base = xo + sl * SLAB_ELEMS + r * 32;
                    *(uint4*)&base[0]  = z;
                    *(uint4*)&base[8]  = z;
                    *(uint4*)&base[16] = z;
                    *(uint4*)&base[24] = z;
                }
            }
        }
        {   // load 64 channels x 256 px into LDS (channel-major), bf16
            const int p4 = (t & 63) * 4;
            const int ci = t >> 6;
            #pragma unroll
            for (int i = 0; i < 16; ++i) {
                const int c = i * 4 + ci;
                floatvec4 v = *(const floatvec4*)&xi[(c0 + c) * 256 + p4];
                unsigned lo = (unsigned)f2bf(v.x) | ((unsigned)f2bf(v.y) << 16);
                unsigned hi = (unsigned)f2bf(v.z) | ((unsigned)f2bf(v.w) << 16);
                *(uint2*)&tile2[c][p4] = make_uint2(lo, hi);
            }
        }
        __syncthreads();
        // write slab layout: 256 core px x 2 local slabs x 4 swizzled 16B units
        #pragma unroll
        for (int it = 0; it < 8; ++it) {
            const int U  = it * 256 + t;
            const int u  = U & 3;
            const int qq = (U >> 2) & 1;
            const int p  = U >> 3;                    // 0..255 core pixel
            const int r  = ((p >> 4) + 1) * 18 + (p & 15) + 1;
            const int ks = (u - ((r >> 1) & 3)) & 3;  // source channel-octet
            const int cb = qq * 32 + ks * 8;
            unsigned v0 = (unsigned)tile2[cb + 0][p] | ((unsigned)tile2[cb + 1][p] << 16);
            unsigned v1 = (unsigned)tile2[cb + 2][p] | ((unsigned)tile2[cb + 3][p] << 16);
            unsigned v2 = (unsigned)tile2[cb + 4][p] | ((unsigned)tile2[cb + 5][p] << 16);
            unsigned v3 = (unsigned)tile2[cb + 6][p] | ((unsigned)tile2[cb + 7][p] << 16);
            const int sl = cy * 2 + qq;
            *(uint4*)&xo[sl * SLAB_ELEMS + r * 32 + u * 8] = make_uint4(v0, v1, v2, v3);
        }
    } else {
        // ---- wprep path (unchanged, verified) ----
        float (*wlds)[257] = (float (*)[257])lds_pool;
        const int w   = bx - 1024;
        const int o16 = (w & 15) * 16;
        const int pos = w >> 4;

        #pragma unroll
        for (int j = 0; j < 16; ++j)
            wlds[j][t] = wt[((o16 + j) * 256 + t) * 9 + pos];

        float a[5];
        {
            float mx = alphas[0];
            #pragma unroll
            for (int i = 1; i < 5; ++i) mx = fmaxf(mx, alphas[i]);
            float s = 0.f;
            #pragma unroll
            for (int i = 0; i < 5; ++i) { a[i] = __expf(alphas[i] - mx); s += a[i]; }
            float inv = 1.f / s;
            #pragma unroll
            for (int i = 0; i < 5; ++i) a[i] *= inv;
        }
        __syncthreads();

        const int c = t;
        #pragma unroll
        for (int oo = 0; oo < 16; ++oo) {
            float acc = a[0] * wlds[oo][c];
            #pragma unroll
            for (int bi = 0; bi < 4; ++bi) {
                const int b  = 2 << bi;            // 2,4,8,16
                const int r  = oo & (b - 1);
                const int cc = c & (b - 1);
                const int i0 = (r - cc) & (b - 1);
                const int ob = oo - r;
                const int icb = c - cc;
                float s2 = 0.f;
                for (int j = 0; j < b; ++j)
                    s2 += wlds[ob + j][icb + ((j + i0) & (b - 1))];
                acc += a[1 + bi] * s2 * (1.f / (float)b);
            }
            w2[(size_t)(o16 + oo) * W2_ROW + pos * 256 + c] = f2bf(acc);
        }
    }
}

// standalone wprep kept only for the small-workspace fallback path
__global__ __launch_bounds__(256) void wprep_kernel(
        const float* __restrict__ wt, const float* __restrict__ alphas,
        unsigned short* __restrict__ w2) {
    __shared__ float wlds[16][257];
    const int o16 = blockIdx.x * 16;
    const int pos = blockIdx.y;
    const int t   = threadIdx.x;
    #pragma unroll
    for (int j = 0; j < 16; ++j)
        wlds[j][t] = wt[((o16 + j) * 256 + t) * 9 + pos];
    float a[5];
    {
        float mx = alphas[0];
        #pragma unroll
        for (int i = 1; i < 5; ++i) mx = fmaxf(mx, alphas[i]);
        float s = 0.f;
        #pragma unroll
        for (int i = 0; i < 5; ++i) { a[i] = __expf(alphas[i] - mx); s += a[i]; }
        float inv = 1.f / s;
        #pragma unroll
        for (int i = 0; i < 5; ++i) a[i] *= inv;
    }
    __syncthreads();
    const int c = t;
    #pragma unroll
    for (int oo = 0; oo < 16; ++oo) {
        float acc = a[0] * wlds[oo][c];
        #pragma unroll
        for (int bi = 0; bi < 4; ++bi) {
            const int b  = 2 << bi;
            const int r  = oo & (b - 1);
            const int cc = c & (b - 1);
            const int i0 = (r - cc) & (b - 1);
            const int ob = oo - r;
            const int icb = c - cc;
            float s2 = 0.f;
            for (int j = 0; j < b; ++j)
                s2 += wlds[ob + j][icb + ((j + i0) & (b - 1))];
            acc += a[1 + bi] * s2 * (1.f / (float)b);
        }
        w2[(size_t)(o16 + oo) * W2_ROW + pos * 256 + c] = f2bf(acc);
    }
}

// ---------------------------------------------------------------------------
// gemm_kernel v9b: v9 with the slab-source fix — global_load_lds needs a
// PER-LANE global address (lane*16 B); v9 passed a wave-uniform one, filling
// the slab with 64 copies of the same 16 B (the absmax-8.0 failure).
// Structure: 2 blocks/CU, grid 512 = (image, pixel-half), 4 waves (2k x 2p),
// per-wave 128x64; B = persistent 10x18x32 slab staged once per c32 (9x less
// DMA than im2col); A = ring-2; v5-proven sync schedule.
// ---------------------------------------------------------------------------
__global__ __launch_bounds__(256, 2) void gemm_kernel(
        const unsigned short* __restrict__ xb,
        const unsigned short* __restrict__ w2,
        float* __restrict__ out) {
    __shared__ __align__(16) unsigned short as0[8192];   // A: 256 rows x 32 elems
    __shared__ __align__(16) unsigned short as1[8192];
    __shared__ __align__(16) unsigned short sl0[6144];   // slab: 192 rows x 32
    __shared__ __align__(16) unsigned short sl1[6144];

    const int t    = threadIdx.x;
    const int lane = t & 63;
    const int wid  = t >> 6;                  // 0..3
    const int bidx = blockIdx.x;
    const int n_img = bidx >> 1;
    const int half  = bidx & 1;               // y in [half*8, half*8+8)

    // ---- A staging addresses (proven formulas; all 4 waves stage A) ----
    const int q     = lane >> 2;
    const int kswz  = ((lane & 3) - ((lane >> 3) & 3)) & 3;
    const int choff = kswz * 8;
    int ag[4];
    #pragma unroll
    for (int i = 0; i < 4; ++i) {
        const int r = wid * 64 + i * 16 + q;          // kout row 0..255
        ag[i] = r * W2_ROW + choff;
    }
    const int adst = wid * 4096;                      // byte offset in A buffer

    // ---- slab staging: 12 linear gloads (3 per wave), PER-LANE source ----
    const size_t slab_base = (size_t)n_img * XB_IMG + (size_t)half * 4608;
    const int sll = lane * 8;                         // lane's 16 B (8 elems)

    // ---- compute setup: wave (wr,wc): kout [wr*128,+128) x pix [wc*64,+64) ----
    const int wr = wid >> 1, wc = wid & 1;
    const int aslot = ((lane >> 1) + (lane >> 4)) & 3;   // proven 0-conflict
    const int aoff  = (wr * 128 + (lane & 15)) * 32 + aslot * 8;
    const int g4    = lane >> 4;                         // k-octet
    int rbase[4];
    #pragma unroll
    for (int nt = 0; nt < 4; ++nt)
        rbase[nt] = (wc * 4 + nt) * 18 + (lane & 15);    // slab row base (dy=dx=0)

    const floatx4 z4 = {0.f, 0.f, 0.f, 0.f};
    floatx4 acc[8][4];
    #pragma unroll
    for (int i = 0; i < 8; ++i)
        #pragma unroll
        for (int j = 0; j < 4; ++j) acc[i][j] = z4;

    // ---- prologue: A(0) and slab(0) in flight, drained by first barrier ----
    #pragma unroll
    for (int i = 0; i < 4; ++i)
        gload_lds16(w2 + ag[i], (char*)as0 + adst + i * 1024);
    #pragma unroll
    for (int j = 0; j < 3; ++j) {
        const int gg = wid * 3 + j;
        gload_lds16(xb + slab_base + gg * 512 + sll, (char*)sl0 + gg * 1024);
    }

    int pos = 0, c32 = 0, sh = 0;
    #pragma unroll 1
    for (int s = 0; s < 72; ++s) {
        __syncthreads();                      // drains loads for step s

        if (s < 71) {                          // issue A(s+1) -> other buffer
            int posn = pos + 1, c32n = c32;
            if (posn == 9) { posn = 0; ++c32n; }
            const int go = posn * 256 + c32n * 32;
            char* dstA = (s & 1) ? (char*)as0 : (char*)as1;
            #pragma unroll
            for (int i = 0; i < 4; ++i)
                gload_lds16(w2 + ag[i] + go, dstA + adst + i * 1024);
        }
        if (pos == 7 && c32 < 7) {             // issue slab(c32+1) -> other slab
            const size_t src = slab_base + (size_t)(c32 + 1) * SLAB_ELEMS;
            char* dstS = (c32 & 1) ? (char*)sl0 : (char*)sl1;
            #pragma unroll
            for (int j = 0; j < 3; ++j) {
                const int gg = wid * 3 + j;
                gload_lds16(xb + src + gg * 512 + sll, dstS + gg * 1024);
            }
        }

        const unsigned short* AS = (s & 1) ? as1 : as0;
        const unsigned short* SL = (c32 & 1) ? sl1 : sl0;

        bf16x8 af[8], bq[4];
        #pragma unroll
        for (int mt = 0; mt < 8; ++mt)
            af[mt] = *(const bf16x8*)&AS[aoff + mt * 512];
        #pragma unroll
        for (int nt = 0; nt < 4; ++nt) {
            const int rl = rbase[nt] + sh;
            const int bo = rl * 32 + ((((rl >> 1) + g4) & 3) << 3);
            bq[nt] = *(const bf16x8*)&SL[bo];
        }

        __builtin_amdgcn_s_setprio(1);
        #pragma unroll
        for (int mt = 0; mt < 8; ++mt)
            #pragma unroll
            for (int nt = 0; nt < 4; ++nt)
                acc[mt][nt] = __builtin_amdgcn_mfma_f32_16x16x32_bf16(
                    af[mt], bq[nt], acc[mt][nt], 0, 0, 0);
        __builtin_amdgcn_s_setprio(0);

        // advance (pos, c32, sh): sh = dy*18+dx = 0,1,2,18,19,20,36,37,38
        ++pos; ++sh;
        if (pos == 3 || pos == 6) sh += 15;
        if (pos == 9) { pos = 0; sh = 0; ++c32; }
    }

    // ---- epilogue: C/D 16x16 layout col=lane&15 (pixel), row=(lane>>4)*4+r
    float* ob = out + (size_t)n_img * 65536;
    const int kb = wr * 128 + (lane >> 4) * 4;
    const int pb = half * 128 + wc * 64 + (lane & 15);
    #pragma unroll
    for (int mt = 0; mt < 8; ++mt)
        #pragma unroll
        for (int nt = 0; nt < 4; ++nt) {
            const int kout = kb + mt * 16;
            const int p    = pb + nt * 16;
            #pragma unroll
            for (int r = 0; r < 4; ++r)
                ob[(size_t)(kout + r) * 256 + p] = acc[mt][nt][r];
        }
}

// ---------------------------------------------------------------------------
// Fallback (only if workspace too small for xb): naive conv using w2.
// ---------------------------------------------------------------------------
__global__ __launch_bounds__(256) void naive_conv(
        const float* __restrict__ x, const unsigned short* __restrict__ w2,
        float* __restrict__ out) {
    __shared__ float wr[2304];
    const int n = blockIdx.x >> 8, k = blockIdx.x & 255;
    const int t = threadIdx.x;
    for (int i = t; i < 2304; i += 256)
        wr[i] = __uint_as_float(((unsigned)w2[k * W2_ROW + i]) << 16);
    __syncthreads();
    const int y = t >> 4, xx = t & 15;
    const float* xi = x + (size_t)n * 65536;
    float acc = 0.f;
    for (int pos = 0; pos < 9; ++pos) {
        int dy = pos / 3 - 1, dx = pos % 3 - 1;
        int yy = y + dy, x2 = xx + dx;
        if (yy < 0 || yy > 15 || x2 < 0 || x2 > 15) continue;
        const float* xp = xi + yy * 16 + x2;
        const float* wp = wr + pos * 256;
        for (int c = 0; c < 256; ++c) acc += xp[c * 256] * wp[c];
    }
    out[(size_t)n * 65536 + k * 256 + t] = acc;
}

extern "C" void kernel_launch(void* const* d_in, const int* in_sizes, int n_in,
                              void* d_out, int out_size, void* d_ws, size_t ws_size,
                              hipStream_t stream) {
    const float* x      = (const float*)d_in[0];
    const float* wt     = (const float*)d_in[1];
    const float* alphas = (const float*)d_in[2];
    float* out = (float*)d_out;

    const size_t xb_elems = (size_t)NIMG * XB_IMG;          // 21,233,664
    const size_t w2_elems = (size_t)256 * W2_ROW;           //    589,824
    const size_t need = (xb_elems + w2_elems) * sizeof(unsigned short);

    if (ws_size >= need) {
        unsigned short* xbp = (unsigned short*)d_ws;
        unsigned short* w2p = xbp + xb_elems;                // right after xb:
        // (gemm's last slab gload overruns xb by 768 B into w2 -- valid memory)
        prep_kernel<<<dim3(1168), 256, 0, stream>>>(x, xbp, wt, alphas, w2p);
        gemm_kernel<<<dim3(512), 256, 0, stream>>>(xbp, w2p, out);
    } else if (ws_size >= w2_elems * sizeof(unsigned short)) {
        unsigned short* w2p = (unsigned short*)d_ws;
        wprep_kernel<<<dim3(16, 9), 256, 0, stream>>>(wt, alphas, w2p);
        naive_conv<<<dim3(256 * 256), 256, 0, stream>>>(x, w2p, out);
    }
}